// Round 9
// baseline (177.387 us; speedup 1.0000x reference)
//
#include <hip/hip_runtime.h>
#include <hip/hip_bf16.h>

#define NCOLS 32768
#define NZ 64
#define NT 40
#define DTF 30.0f
#define GAMMAC 0.55f

typedef _Float16 f16;

// Cap the pre-RA scheduler's prefetch window (r4->r5 lesson: unbounded
// ds_read hoisting inflates live ranges past the VGPR budget -> scratch).
#define SBAR() __builtin_amdgcn_sched_barrier(0)

// lane^1 within quad: u<->v (t<->s) partner
__device__ __forceinline__ float dpp1(float x) {
    return __int_as_float(__builtin_amdgcn_mov_dpp(__float_as_int(x), 0xB1, 0xF, 0xF, true));
}
// lane^2 within quad: top<->bottom half exchange
__device__ __forceinline__ float dpp2(float x) {
    return __int_as_float(__builtin_amdgcn_mov_dpp(__float_as_int(x), 0x4E, 0xF, 0xF, true));
}
__device__ __forceinline__ unsigned int packh2(float a, float b) {
    union { f16 h[2]; unsigned int u; } v;
    v.h[0] = (f16)a; v.h[1] = (f16)b; return v.u;
}
__device__ __forceinline__ unsigned short f16bits(float a) {
    union { f16 h; unsigned short u; } v; v.h = (f16)a; return v.u;
}
__device__ __forceinline__ float lo16f(unsigned int x) {
    union { unsigned int u; f16 h[2]; } v; v.u = x; return (float)v.h[0];
}
__device__ __forceinline__ float hi16f(unsigned int x) {
    union { unsigned int u; f16 h[2]; } v; v.u = x; return (float)v.h[1];
}

// BABE (burning-at-both-ends) Thomas: 2 threads per (col,field) eliminate
// from both ends, meet at a 2x2 junction (k=31|32), substitute outward.
// In local order j (top: k=j; bottom: k=63-j) both halves run IDENTICAL
// code: W=(hz*g, -carry*g), CP=(-adj*g), chain dp[j]=W.lo*m+fg - W.hi... etc.
// Lane quad = (u-top, v-top, u-bot, v-bot); next quad = (t,s) same.
// LDS 40KB/block -> 4 blocks/CU = 16 waves/CU (was 8); chain 128->64.
__global__ __launch_bounds__(256, 4) void scm_kernel(
    const float* __restrict__ u0, const float* __restrict__ v0,
    const float* __restrict__ t0, const float* __restrict__ s0,
    const float* __restrict__ hz, const float* __restrict__ akv,
    const float* __restrict__ akt, const float* __restrict__ tfo,
    const float* __restrict__ sfo, const float* __restrict__ uss,
    const float* __restrict__ vss, const float* __restrict__ usb,
    const float* __restrict__ vsb, const float* __restrict__ fcor,
    float* __restrict__ out)
{
    __shared__ uint4 Wsh[8 * 128];   // [j4][slot] 4 levels (hg,-e)|(hq,-cq) = 16KB
    __shared__ uint2 CPsh[8 * 128];  // [j4][slot] 4 levels -cp|-eq          =  8KB
    __shared__ uint2 FGsh[8 * 256];  // [j4][ltid] 4 levels fg               = 16KB

    const int ltid = threadIdx.x;
    const int cb   = ltid >> 3;            // column in block 0..31
    const int sub  = ltid & 7;
    const int f01  = sub & 1;              // 0: u/t   1: v/s
    const int half = (sub >> 1) & 1;       // 0: top(k=0..31) 1: bottom(k=63..32)
    const int pr   = sub >> 2;             // 0: uv (akv)  1: ts (akt)
    const int field = pr * 2 + f01;
    const int col  = blockIdx.x * 32 + cb;
    const int slot = (cb << 2) | (pr << 1) | half;   // 0..127 (shared by f01 pair)
    const int dir  = half ? -1 : 1;
    const int kb   = half ? 63 : 0;

    const float* ak  = pr ? akt : akv;
    const float* st0 = (field == 0) ? u0 : (field == 1) ? v0
                     : (field == 2) ? t0 : s0;

    // Coriolis scalars + boundary forcing (uv lanes; ts: alpha=1,beta=0)
    float alpha = 1.0f, beta = 0.0f, bndv = 0.0f;
    {
        float fc   = fcor[col];
        float dtfc = DTF * fc;
        float cff  = dtfc * dtfc;
        float cff1 = 1.0f / (1.0f + GAMMAC * GAMMAC * cff);
        float coefc = 1.0f - GAMMAC * (1.0f - GAMMAC) * cff;
        if (!pr) {
            alpha = cff1 * coefc;
            beta  = f01 ? -cff1 * dtfc : cff1 * dtfc;
            bndv  = half ?  DTF * ((f01 ? vss : uss)[col])
                         : -DTF * ((f01 ? vsb : usb)[col]);
        }
    }

    const float* hzc = hz + (size_t)col * NZ;
    const float* akp = ak + (size_t)col * (NZ + 1) + (half ? 63 : 1);
    const float* frp = ((f01 ? sfo : tfo)) + (size_t)col * NZ + kb; // uv lanes: harmless reads
    const float* hzp = hzc + kb + dir;

    // ---- build (each half builds its own 32 levels; fully uniform) ----
    float cpn_own = 0.0f;   // junction: top -cp[31], bottom -eq[32] (f32)
    {
        float chainprev = 0.f, carry = 0.f;
        float hk = hzc[kb];
        uint4 wacc = {};
        uint2 cpacc = {}, fgacc = {};
        #pragma unroll
        for (int j = 0; j < 32; ++j) {
            float hnx = *hzp;
            float adj = (-2.0f * DTF) * (*akp) / (hk + hnx);  // link to next local level
            float b   = hk - carry - adj;
            float g   = 1.0f / (b - carry * chainprev);
            float fgk = pr ? (DTF * (*frp)) * g
                           : ((j == 0) ? bndv * g : 0.0f);
            unsigned int   wv  = packh2(hk * g, -carry * g);
            float          cpn = -(adj * g);
            unsigned short cv  = f16bits(cpn);
            unsigned short fv  = f16bits(fgk);
            switch (j & 3) {
                case 0: wacc.x = wv; cpacc.x = cv; fgacc.x = fv; break;
                case 1: wacc.y = wv; cpacc.x |= ((unsigned int)cv << 16);
                        fgacc.x |= ((unsigned int)fv << 16); break;
                case 2: wacc.z = wv; cpacc.y = cv; fgacc.y = fv; break;
                default:
                    wacc.w = wv; cpacc.y |= ((unsigned int)cv << 16);
                    fgacc.y |= ((unsigned int)fv << 16);
                    FGsh[(j >> 2) * 256 + ltid] = fgacc;
                    if (f01 == 0) {
                        Wsh[(j >> 2) * 128 + slot]  = wacc;
                        CPsh[(j >> 2) * 128 + slot] = cpacc;
                    }
                    break;
            }
            if (j == 31) cpn_own = cpn;
            chainprev = adj * g; carry = adj; hk = hnx;
            hzp += dir; akp += dir; frp += dir;
            if ((j & 15) == 15) SBAR();
        }
    }

    // junction constants: s = 1/(1 - cp31*eq32), both sides hold both coeffs
    float cpn_oth = dpp2(cpn_own);
    float cptop   = half ? cpn_oth : cpn_own;
    float cpbot   = half ? cpn_own : cpn_oth;
    float smid    = 1.0f / (1.0f - cptop * cpbot);

    // ---- load state (local order; bottom reversed) ----
    float tau[32];
    {
        const float4* sp = (const float4*)(st0 + (size_t)col * NZ);
        if (!half) {
            #pragma unroll
            for (int q = 0; q < 8; ++q) {
                float4 v = sp[q];
                tau[4*q+0] = v.x; tau[4*q+1] = v.y;
                tau[4*q+2] = v.z; tau[4*q+3] = v.w;
            }
        } else {
            #pragma unroll
            for (int q = 0; q < 8; ++q) {
                float4 v = sp[15 - q];
                tau[4*q+0] = v.w; tau[4*q+1] = v.z;
                tau[4*q+2] = v.y; tau[4*q+3] = v.x;
            }
        }
    }

    // deviation shift for t,s (solve conserves constants): column mean needs
    // both halves -> one dpp2 exchange of the partial sums.
    float meanadd = 0.0f;
    {
        float ss = 0.f;
        #pragma unroll
        for (int j = 0; j < 32; ++j) ss += tau[j];
        float tot = ss + dpp2(ss);
        if (pr) {
            meanadd = tot * (1.0f / 64.0f);
            #pragma unroll
            for (int j = 0; j < 32; ++j) tau[j] -= meanadd;
        }
    }

    __syncthreads();   // coefficients published; LDS read-only from here on

    // ---- 40 time steps ----
    for (int n = 0; n < NT; ++n) {
        // elimination sweep (both halves toward the junction)
        float dpprev = 0.f;
        #pragma unroll
        for (int q = 0; q < 8; ++q) {
            uint4 w  = Wsh[q * 128 + slot];
            uint2 f4 = FGsh[q * 256 + ltid];
            #pragma unroll
            for (int i = 0; i < 4; ++i) {
                unsigned int wv = (i == 0) ? w.x : (i == 1) ? w.y
                                : (i == 2) ? w.z : w.w;
                float fgv = (i == 0) ? lo16f(f4.x) : (i == 1) ? hi16f(f4.x)
                          : (i == 2) ? lo16f(f4.y) : hi16f(f4.y);
                float own = tau[4*q + i];
                float oth = dpp1(own);                    // u<->v partner
                float m   = fmaf(beta, oth, alpha * own); // ts: beta=0,alpha=1
                float dp  = fmaf(hi16f(wv), dpprev, fmaf(lo16f(wv), m, fgv));
                tau[4*q + i] = dp;
                dpprev = dp;
            }
            if ((q & 3) == 3) SBAR();
        }
        // junction 2x2: x31 = s*(dp31 - cp31*dq32); x32 = dq32 - eq32*x31
        float other = dpp2(dpprev);
        float dtp = half ? other : dpprev;    // dp31
        float dbt = half ? dpprev : other;    // dq32
        float x31 = smid * fmaf(cptop, dbt, dtp);
        float xj  = half ? fmaf(cpn_own, x31, dpprev) : x31;
        tau[31] = xj;
        // substitution outward (both halves away from the junction)
        float xn = xj;
        #pragma unroll
        for (int q = 7; q >= 0; --q) {
            uint2 c4 = CPsh[q * 128 + slot];
            #pragma unroll
            for (int i = 3; i >= 0; --i) {
                const int j = 4*q + i;
                if (j == 31) continue;        // junction already solved
                float cv = (i == 0) ? lo16f(c4.x) : (i == 1) ? hi16f(c4.x)
                         : (i == 2) ? lo16f(c4.y) : hi16f(c4.y);
                float x = fmaf(cv, xn, tau[j]);
                tau[j] = x;
                xn = x;
            }
            if ((q & 3) == 0) SBAR();
        }
    }

    // ---- store f32 output: out[field][col][k] (bottom reversed) ----
    float* op = out + ((size_t)field * NCOLS + col) * NZ;
    if (!half) {
        #pragma unroll
        for (int q = 0; q < 8; ++q) {
            float4 w;
            w.x = tau[4*q+0] + meanadd; w.y = tau[4*q+1] + meanadd;
            w.z = tau[4*q+2] + meanadd; w.w = tau[4*q+3] + meanadd;
            ((float4*)op)[q] = w;
        }
    } else {
        #pragma unroll
        for (int q = 0; q < 8; ++q) {
            float4 w;
            w.x = tau[4*q+3] + meanadd; w.y = tau[4*q+2] + meanadd;
            w.z = tau[4*q+1] + meanadd; w.w = tau[4*q+0] + meanadd;
            ((float4*)op)[15 - q] = w;
        }
    }
}

extern "C" void kernel_launch(void* const* d_in, const int* in_sizes, int n_in,
                              void* d_out, int out_size, void* d_ws, size_t ws_size,
                              hipStream_t stream) {
    const float* u0   = (const float*)d_in[0];
    const float* v0   = (const float*)d_in[1];
    const float* t0   = (const float*)d_in[2];
    const float* s0   = (const float*)d_in[3];
    const float* hz   = (const float*)d_in[4];
    const float* akv  = (const float*)d_in[5];
    const float* akt  = (const float*)d_in[6];
    const float* tfo  = (const float*)d_in[7];
    const float* sfo  = (const float*)d_in[8];
    const float* uss  = (const float*)d_in[9];
    const float* vss  = (const float*)d_in[10];
    const float* usb  = (const float*)d_in[11];
    const float* vsb  = (const float*)d_in[12];
    const float* fcor = (const float*)d_in[13];

    scm_kernel<<<dim3(NCOLS / 32), dim3(256), 0, stream>>>(
        u0, v0, t0, s0, hz, akv, akt, tfo, sfo, uss, vss, usb, vsb, fcor,
        (float*)d_out);
}

// Round 10
// 171.879 us; speedup vs baseline: 1.0320x; 1.0320x over previous
//
#include <hip/hip_runtime.h>
#include <hip/hip_bf16.h>

#define NCOLS 32768
#define NZ 64
#define NT 40
#define DTF 30.0f
#define GAMMAC 0.55f

typedef _Float16 f16;

// Cap the pre-RA scheduler's prefetch window (r4->r5 lesson: unbounded
// ds_read hoisting inflates live ranges past the VGPR budget -> scratch).
#define SBAR() __builtin_amdgcn_sched_barrier(0)

// lane^1 within quad: u<->v (t<->s) partner
__device__ __forceinline__ float dpp1(float x) {
    return __int_as_float(__builtin_amdgcn_mov_dpp(__float_as_int(x), 0xB1, 0xF, 0xF, true));
}
// lane^2 within quad: top<->bottom half exchange
__device__ __forceinline__ float dpp2(float x) {
    return __int_as_float(__builtin_amdgcn_mov_dpp(__float_as_int(x), 0x4E, 0xF, 0xF, true));
}
__device__ __forceinline__ unsigned int packh2(float a, float b) {
    union { f16 h[2]; unsigned int u; } v;
    v.h[0] = (f16)a; v.h[1] = (f16)b; return v.u;
}
__device__ __forceinline__ unsigned short f16bits(float a) {
    union { f16 h; unsigned short u; } v; v.h = (f16)a; return v.u;
}
__device__ __forceinline__ float lo16f(unsigned int x) {
    union { unsigned int u; f16 h[2]; } v; v.u = x; return (float)v.h[0];
}
__device__ __forceinline__ float hi16f(unsigned int x) {
    union { unsigned int u; f16 h[2]; } v; v.u = x; return (float)v.h[1];
}

// BABE (burning-at-both-ends) Thomas: 2 threads per (col,field) eliminate
// from both ends, meet at a 2x2 junction (k=31|32), substitute outward.
// In local order j (top: k=j; bottom: k=63-j) both halves run IDENTICAL
// code. Lane quad = (u-top, v-top, u-bot, v-bot); next quad = (t,s) same.
// LDS 40KB/block -> 4 blocks/CU = 16 waves/CU; dependent chain 128->64.
//
// Allocator law (r2-r9): launch_bounds(256,2) -> grants ~88-128 VGPRs;
// launch_bounds(256,4) made the perf-hint heuristic target ~9 waves/EU and
// clamp at 56 VGPRs, re-spilling tau (316MB FETCH, r9). Demand here ~70,
// so (256,2) -> no spill; real occupancy is LDS-limited at 4 blocks/CU.
__global__ __launch_bounds__(256, 2) void scm_kernel(
    const float* __restrict__ u0, const float* __restrict__ v0,
    const float* __restrict__ t0, const float* __restrict__ s0,
    const float* __restrict__ hz, const float* __restrict__ akv,
    const float* __restrict__ akt, const float* __restrict__ tfo,
    const float* __restrict__ sfo, const float* __restrict__ uss,
    const float* __restrict__ vss, const float* __restrict__ usb,
    const float* __restrict__ vsb, const float* __restrict__ fcor,
    float* __restrict__ out)
{
    __shared__ uint4 Wsh[8 * 128];   // [j4][slot] 4 levels (hg,-e)|(hq,-cq) = 16KB
    __shared__ uint2 CPsh[8 * 128];  // [j4][slot] 4 levels -cp|-eq          =  8KB
    __shared__ uint2 FGsh[8 * 256];  // [j4][ltid] 4 levels fg               = 16KB

    const int ltid = threadIdx.x;
    const int cb   = ltid >> 3;            // column in block 0..31
    const int sub  = ltid & 7;
    const int f01  = sub & 1;              // 0: u/t   1: v/s
    const int half = (sub >> 1) & 1;       // 0: top(k=0..31) 1: bottom(k=63..32)
    const int pr   = sub >> 2;             // 0: uv (akv)  1: ts (akt)
    const int field = pr * 2 + f01;
    const int col  = blockIdx.x * 32 + cb;
    const int slot = (cb << 2) | (pr << 1) | half;   // 0..127 (shared by f01 pair)
    const int dir  = half ? -1 : 1;
    const int kb   = half ? 63 : 0;

    const float* ak  = pr ? akt : akv;
    const float* st0 = (field == 0) ? u0 : (field == 1) ? v0
                     : (field == 2) ? t0 : s0;

    // Coriolis scalars + boundary forcing (uv lanes; ts: alpha=1,beta=0)
    float alpha = 1.0f, beta = 0.0f, bndv = 0.0f;
    {
        float fc   = fcor[col];
        float dtfc = DTF * fc;
        float cff  = dtfc * dtfc;
        float cff1 = 1.0f / (1.0f + GAMMAC * GAMMAC * cff);
        float coefc = 1.0f - GAMMAC * (1.0f - GAMMAC) * cff;
        if (!pr) {
            alpha = cff1 * coefc;
            beta  = f01 ? -cff1 * dtfc : cff1 * dtfc;
            bndv  = half ?  DTF * ((f01 ? vss : uss)[col])
                         : -DTF * ((f01 ? vsb : usb)[col]);
        }
    }

    const float* hzc = hz + (size_t)col * NZ;
    const float* akp = ak + (size_t)col * (NZ + 1) + (half ? 63 : 1);
    const float* frp = ((f01 ? sfo : tfo)) + (size_t)col * NZ + kb; // uv lanes: harmless reads
    const float* hzp = hzc + kb + dir;

    // ---- build (each half builds its own 32 levels; fully uniform) ----
    float cpn_own = 0.0f;   // junction: top -cp[31], bottom -eq[32] (f32)
    {
        float chainprev = 0.f, carry = 0.f;
        float hk = hzc[kb];
        uint4 wacc = {};
        uint2 cpacc = {}, fgacc = {};
        #pragma unroll
        for (int j = 0; j < 32; ++j) {
            float hnx = *hzp;
            float adj = (-2.0f * DTF) * (*akp) / (hk + hnx);  // link to next local level
            float b   = hk - carry - adj;
            float g   = 1.0f / (b - carry * chainprev);
            float fgk = pr ? (DTF * (*frp)) * g
                           : ((j == 0) ? bndv * g : 0.0f);
            unsigned int   wv  = packh2(hk * g, -carry * g);
            float          cpn = -(adj * g);
            unsigned short cv  = f16bits(cpn);
            unsigned short fv  = f16bits(fgk);
            switch (j & 3) {
                case 0: wacc.x = wv; cpacc.x = cv; fgacc.x = fv; break;
                case 1: wacc.y = wv; cpacc.x |= ((unsigned int)cv << 16);
                        fgacc.x |= ((unsigned int)fv << 16); break;
                case 2: wacc.z = wv; cpacc.y = cv; fgacc.y = fv; break;
                default:
                    wacc.w = wv; cpacc.y |= ((unsigned int)cv << 16);
                    fgacc.y |= ((unsigned int)fv << 16);
                    FGsh[(j >> 2) * 256 + ltid] = fgacc;
                    if (f01 == 0) {
                        Wsh[(j >> 2) * 128 + slot]  = wacc;
                        CPsh[(j >> 2) * 128 + slot] = cpacc;
                    }
                    break;
            }
            if (j == 31) cpn_own = cpn;
            chainprev = adj * g; carry = adj; hk = hnx;
            hzp += dir; akp += dir; frp += dir;
            if ((j & 15) == 15) SBAR();
        }
    }

    // junction constants: s = 1/(1 - cp31*eq32), both sides hold both coeffs
    float cpn_oth = dpp2(cpn_own);
    float cptop   = half ? cpn_oth : cpn_own;
    float cpbot   = half ? cpn_own : cpn_oth;
    float smid    = 1.0f / (1.0f - cptop * cpbot);

    // ---- load state (local order; bottom reversed) ----
    float tau[32];
    {
        const float4* sp = (const float4*)(st0 + (size_t)col * NZ);
        if (!half) {
            #pragma unroll
            for (int q = 0; q < 8; ++q) {
                float4 v = sp[q];
                tau[4*q+0] = v.x; tau[4*q+1] = v.y;
                tau[4*q+2] = v.z; tau[4*q+3] = v.w;
            }
        } else {
            #pragma unroll
            for (int q = 0; q < 8; ++q) {
                float4 v = sp[15 - q];
                tau[4*q+0] = v.w; tau[4*q+1] = v.z;
                tau[4*q+2] = v.y; tau[4*q+3] = v.x;
            }
        }
    }

    // deviation shift for t,s (solve conserves constants): column mean needs
    // both halves -> one dpp2 exchange of the partial sums.
    float meanadd = 0.0f;
    {
        float ss = 0.f;
        #pragma unroll
        for (int j = 0; j < 32; ++j) ss += tau[j];
        float tot = ss + dpp2(ss);
        if (pr) {
            meanadd = tot * (1.0f / 64.0f);
            #pragma unroll
            for (int j = 0; j < 32; ++j) tau[j] -= meanadd;
        }
    }

    __syncthreads();   // coefficients published; LDS read-only from here on

    // ---- 40 time steps ----
    for (int n = 0; n < NT; ++n) {
        // elimination sweep (both halves toward the junction)
        float dpprev = 0.f;
        #pragma unroll
        for (int q = 0; q < 8; ++q) {
            uint4 w  = Wsh[q * 128 + slot];
            uint2 f4 = FGsh[q * 256 + ltid];
            #pragma unroll
            for (int i = 0; i < 4; ++i) {
                unsigned int wv = (i == 0) ? w.x : (i == 1) ? w.y
                                : (i == 2) ? w.z : w.w;
                float fgv = (i == 0) ? lo16f(f4.x) : (i == 1) ? hi16f(f4.x)
                          : (i == 2) ? lo16f(f4.y) : hi16f(f4.y);
                float own = tau[4*q + i];
                float oth = dpp1(own);                    // u<->v partner
                float m   = fmaf(beta, oth, alpha * own); // ts: beta=0,alpha=1
                float dp  = fmaf(hi16f(wv), dpprev, fmaf(lo16f(wv), m, fgv));
                tau[4*q + i] = dp;
                dpprev = dp;
            }
            if ((q & 3) == 3) SBAR();
        }
        // junction 2x2: x31 = s*(dp31 - cp31*dq32); x32 = dq32 - eq32*x31
        float other = dpp2(dpprev);
        float dtp = half ? other : dpprev;    // dp31
        float dbt = half ? dpprev : other;    // dq32
        float x31 = smid * fmaf(cptop, dbt, dtp);
        float xj  = half ? fmaf(cpn_own, x31, dpprev) : x31;
        tau[31] = xj;
        // substitution outward (both halves away from the junction)
        float xn = xj;
        #pragma unroll
        for (int q = 7; q >= 0; --q) {
            uint2 c4 = CPsh[q * 128 + slot];
            #pragma unroll
            for (int i = 3; i >= 0; --i) {
                const int j = 4*q + i;
                if (j == 31) continue;        // junction already solved
                float cv = (i == 0) ? lo16f(c4.x) : (i == 1) ? hi16f(c4.x)
                         : (i == 2) ? lo16f(c4.y) : hi16f(c4.y);
                float x = fmaf(cv, xn, tau[j]);
                tau[j] = x;
                xn = x;
            }
            if ((q & 3) == 0) SBAR();
        }
    }

    // ---- store f32 output: out[field][col][k] (bottom reversed) ----
    float* op = out + ((size_t)field * NCOLS + col) * NZ;
    if (!half) {
        #pragma unroll
        for (int q = 0; q < 8; ++q) {
            float4 w;
            w.x = tau[4*q+0] + meanadd; w.y = tau[4*q+1] + meanadd;
            w.z = tau[4*q+2] + meanadd; w.w = tau[4*q+3] + meanadd;
            ((float4*)op)[q] = w;
        }
    } else {
        #pragma unroll
        for (int q = 0; q < 8; ++q) {
            float4 w;
            w.x = tau[4*q+3] + meanadd; w.y = tau[4*q+2] + meanadd;
            w.z = tau[4*q+1] + meanadd; w.w = tau[4*q+0] + meanadd;
            ((float4*)op)[15 - q] = w;
        }
    }
}

extern "C" void kernel_launch(void* const* d_in, const int* in_sizes, int n_in,
                              void* d_out, int out_size, void* d_ws, size_t ws_size,
                              hipStream_t stream) {
    const float* u0   = (const float*)d_in[0];
    const float* v0   = (const float*)d_in[1];
    const float* t0   = (const float*)d_in[2];
    const float* s0   = (const float*)d_in[3];
    const float* hz   = (const float*)d_in[4];
    const float* akv  = (const float*)d_in[5];
    const float* akt  = (const float*)d_in[6];
    const float* tfo  = (const float*)d_in[7];
    const float* sfo  = (const float*)d_in[8];
    const float* uss  = (const float*)d_in[9];
    const float* vss  = (const float*)d_in[10];
    const float* usb  = (const float*)d_in[11];
    const float* vsb  = (const float*)d_in[12];
    const float* fcor = (const float*)d_in[13];

    scm_kernel<<<dim3(NCOLS / 32), dim3(256), 0, stream>>>(
        u0, v0, t0, s0, hz, akv, akt, tfo, sfo, uss, vss, usb, vsb, fcor,
        (float*)d_out);
}

// Round 11
// 143.292 us; speedup vs baseline: 1.2379x; 1.1995x over previous
//
#include <hip/hip_runtime.h>
#include <hip/hip_bf16.h>

#define NCOLS 32768
#define NZ 64
#define NT 40
#define DTF 30.0f
#define GAMMAC 0.55f

typedef _Float16 f16;

// Cap the pre-RA scheduler's prefetch window (r4->r5 lesson: unbounded
// ds_read hoisting inflates live ranges past the VGPR budget -> scratch).
#define SBAR() __builtin_amdgcn_sched_barrier(0)

// lane^1 within quad: u<->v (t<->s) partner
__device__ __forceinline__ float dpp1(float x) {
    return __int_as_float(__builtin_amdgcn_mov_dpp(__float_as_int(x), 0xB1, 0xF, 0xF, true));
}
// lane^2 within quad: top<->bottom half exchange
__device__ __forceinline__ float dpp2(float x) {
    return __int_as_float(__builtin_amdgcn_mov_dpp(__float_as_int(x), 0x4E, 0xF, 0xF, true));
}
__device__ __forceinline__ unsigned int packh2(float a, float b) {
    union { f16 h[2]; unsigned int u; } v;
    v.h[0] = (f16)a; v.h[1] = (f16)b; return v.u;
}
__device__ __forceinline__ unsigned short f16bits(float a) {
    union { f16 h; unsigned short u; } v; v.h = (f16)a; return v.u;
}
__device__ __forceinline__ float lo16f(unsigned int x) {
    union { unsigned int u; f16 h[2]; } v; v.u = x; return (float)v.h[0];
}
__device__ __forceinline__ float hi16f(unsigned int x) {
    union { unsigned int u; f16 h[2]; } v; v.u = x; return (float)v.h[1];
}

// BABE (burning-at-both-ends) Thomas: 2 threads per (col,field) eliminate
// from both ends, meet at a 2x2 junction (k=31|32), substitute outward.
// Lane quad = (u-top, v-top, u-bot, v-bot); next quad = (t,s) same.
//
// Allocator clamp forensics (r9/r10: VGPR clamped to 56, 300MB spill):
// no-clamp kernels (r5/r7/r8, granted 88) all had {LDS>=64KB, affine
// build addressing}; clamped ones had {40KB LDS, runtime-stride pointer
// walks}. This version restores BOTH: 512-thread blocks (64 cols) -> real
// 80KB LDS (2 blocks/CU x 8 waves = 16 waves/CU, BABE's occupancy goal),
// and top/bottom build loops with LITERAL strides (divergent once-only
// build; solver loop unchanged and wave-uniform).
__global__ __launch_bounds__(512, 2) void scm_kernel(
    const float* __restrict__ u0, const float* __restrict__ v0,
    const float* __restrict__ t0, const float* __restrict__ s0,
    const float* __restrict__ hz, const float* __restrict__ akv,
    const float* __restrict__ akt, const float* __restrict__ tfo,
    const float* __restrict__ sfo, const float* __restrict__ uss,
    const float* __restrict__ vss, const float* __restrict__ usb,
    const float* __restrict__ vsb, const float* __restrict__ fcor,
    float* __restrict__ out)
{
    __shared__ uint4 Wsh[8 * 256];   // [j4][slot] 4 levels (hg,-e)  = 32KB
    __shared__ uint2 CPsh[8 * 256];  // [j4][slot] 4 levels -cp|-eq  = 16KB
    __shared__ uint2 FGsh[8 * 512];  // [j4][ltid] 4 levels fg       = 32KB

    const int ltid = threadIdx.x;
    const int cb   = ltid >> 3;            // column in block 0..63
    const int sub  = ltid & 7;
    const int f01  = sub & 1;              // 0: u/t   1: v/s
    const int half = (sub >> 1) & 1;       // 0: top(k=0..31) 1: bottom(k=63..32)
    const int pr   = sub >> 2;             // 0: uv (akv)  1: ts (akt)
    const int field = pr * 2 + f01;
    const int col  = blockIdx.x * 64 + cb;
    const int slot = (cb << 2) | (pr << 1) | half;   // 0..255 (f01 pair shares)

    const float* ak  = pr ? akt : akv;
    const float* st0 = (field == 0) ? u0 : (field == 1) ? v0
                     : (field == 2) ? t0 : s0;

    // Coriolis scalars + boundary forcing (uv lanes; ts: alpha=1,beta=0)
    float alpha = 1.0f, beta = 0.0f, bndv = 0.0f;
    {
        float fc   = fcor[col];
        float dtfc = DTF * fc;
        float cff  = dtfc * dtfc;
        float cff1 = 1.0f / (1.0f + GAMMAC * GAMMAC * cff);
        float coefc = 1.0f - GAMMAC * (1.0f - GAMMAC) * cff;
        if (!pr) {
            alpha = cff1 * coefc;
            beta  = f01 ? -cff1 * dtfc : cff1 * dtfc;
            bndv  = half ?  DTF * ((f01 ? vss : uss)[col])
                         : -DTF * ((f01 ? vsb : usb)[col]);
        }
    }

    const float* hzc = hz + (size_t)col * NZ;
    const float* akc = ak + (size_t)col * (NZ + 1);
    const float* frc = (f01 ? sfo : tfo) + (size_t)col * NZ;

    // ---- build: affine indexing, separate top/bottom loops ----
    float cpn_own = 0.0f;   // junction: top -cp[31], bottom -eq[32] (f32)
    if (!half) {
        float chainprev = 0.f, carry = 0.f, hk = hzc[0];
        uint4 wacc = {}; uint2 cpacc = {}, fgacc = {};
        #pragma unroll
        for (int j = 0; j < 32; ++j) {
            float hnx = hzc[j + 1];
            float adj = (-2.0f * DTF) * akc[j + 1] / (hk + hnx);
            float b   = hk - carry - adj;
            float g   = 1.0f / (b - carry * chainprev);
            float fgk = pr ? (DTF * frc[j]) * g
                           : ((j == 0) ? bndv * g : 0.0f);
            unsigned int   wv  = packh2(hk * g, -carry * g);
            float          cpn = -(adj * g);
            unsigned short cv  = f16bits(cpn);
            unsigned short fv  = f16bits(fgk);
            switch (j & 3) {
                case 0: wacc.x = wv; cpacc.x = cv; fgacc.x = fv; break;
                case 1: wacc.y = wv; cpacc.x |= ((unsigned int)cv << 16);
                        fgacc.x |= ((unsigned int)fv << 16); break;
                case 2: wacc.z = wv; cpacc.y = cv; fgacc.y = fv; break;
                default:
                    wacc.w = wv; cpacc.y |= ((unsigned int)cv << 16);
                    fgacc.y |= ((unsigned int)fv << 16);
                    FGsh[(j >> 2) * 512 + ltid] = fgacc;
                    if (f01 == 0) {
                        Wsh[(j >> 2) * 256 + slot]  = wacc;
                        CPsh[(j >> 2) * 256 + slot] = cpacc;
                    }
                    break;
            }
            if (j == 31) cpn_own = cpn;
            chainprev = adj * g; carry = adj; hk = hnx;
            if ((j & 15) == 15) SBAR();
        }
    } else {
        float chainprev = 0.f, carry = 0.f, hk = hzc[63];
        uint4 wacc = {}; uint2 cpacc = {}, fgacc = {};
        #pragma unroll
        for (int j = 0; j < 32; ++j) {
            float hnx = hzc[62 - j];
            float adj = (-2.0f * DTF) * akc[63 - j] / (hk + hnx);
            float b   = hk - carry - adj;
            float g   = 1.0f / (b - carry * chainprev);
            float fgk = pr ? (DTF * frc[63 - j]) * g
                           : ((j == 0) ? bndv * g : 0.0f);
            unsigned int   wv  = packh2(hk * g, -carry * g);
            float          cpn = -(adj * g);
            unsigned short cv  = f16bits(cpn);
            unsigned short fv  = f16bits(fgk);
            switch (j & 3) {
                case 0: wacc.x = wv; cpacc.x = cv; fgacc.x = fv; break;
                case 1: wacc.y = wv; cpacc.x |= ((unsigned int)cv << 16);
                        fgacc.x |= ((unsigned int)fv << 16); break;
                case 2: wacc.z = wv; cpacc.y = cv; fgacc.y = fv; break;
                default:
                    wacc.w = wv; cpacc.y |= ((unsigned int)cv << 16);
                    fgacc.y |= ((unsigned int)fv << 16);
                    FGsh[(j >> 2) * 512 + ltid] = fgacc;
                    if (f01 == 0) {
                        Wsh[(j >> 2) * 256 + slot]  = wacc;
                        CPsh[(j >> 2) * 256 + slot] = cpacc;
                    }
                    break;
            }
            if (j == 31) cpn_own = cpn;
            chainprev = adj * g; carry = adj; hk = hnx;
            if ((j & 15) == 15) SBAR();
        }
    }

    // junction constants: s = 1/(1 - cp31*eq32), both sides hold both coeffs
    float cpn_oth = dpp2(cpn_own);
    float cptop   = half ? cpn_oth : cpn_own;
    float cpbot   = half ? cpn_own : cpn_oth;
    float smid    = 1.0f / (1.0f - cptop * cpbot);

    // ---- load state (local order; bottom reversed; affine) ----
    float tau[32];
    {
        const float4* sp = (const float4*)(st0 + (size_t)col * NZ);
        if (!half) {
            #pragma unroll
            for (int q = 0; q < 8; ++q) {
                float4 v = sp[q];
                tau[4*q+0] = v.x; tau[4*q+1] = v.y;
                tau[4*q+2] = v.z; tau[4*q+3] = v.w;
            }
        } else {
            #pragma unroll
            for (int q = 0; q < 8; ++q) {
                float4 v = sp[15 - q];
                tau[4*q+0] = v.w; tau[4*q+1] = v.z;
                tau[4*q+2] = v.y; tau[4*q+3] = v.x;
            }
        }
    }

    // deviation shift for t,s (solve conserves constants): column mean needs
    // both halves -> one dpp2 exchange of the partial sums.
    float meanadd = 0.0f;
    {
        float ss = 0.f;
        #pragma unroll
        for (int j = 0; j < 32; ++j) ss += tau[j];
        float tot = ss + dpp2(ss);
        if (pr) {
            meanadd = tot * (1.0f / 64.0f);
            #pragma unroll
            for (int j = 0; j < 32; ++j) tau[j] -= meanadd;
        }
    }

    __syncthreads();   // coefficients published; LDS read-only from here on

    // ---- 40 time steps ----
    for (int n = 0; n < NT; ++n) {
        // elimination sweep (both halves toward the junction; wave-uniform)
        float dpprev = 0.f;
        #pragma unroll
        for (int q = 0; q < 8; ++q) {
            uint4 w  = Wsh[q * 256 + slot];
            uint2 f4 = FGsh[q * 512 + ltid];
            #pragma unroll
            for (int i = 0; i < 4; ++i) {
                unsigned int wv = (i == 0) ? w.x : (i == 1) ? w.y
                                : (i == 2) ? w.z : w.w;
                float fgv = (i == 0) ? lo16f(f4.x) : (i == 1) ? hi16f(f4.x)
                          : (i == 2) ? lo16f(f4.y) : hi16f(f4.y);
                float own = tau[4*q + i];
                float oth = dpp1(own);                    // u<->v partner
                float m   = fmaf(beta, oth, alpha * own); // ts: beta=0,alpha=1
                float dp  = fmaf(hi16f(wv), dpprev, fmaf(lo16f(wv), m, fgv));
                tau[4*q + i] = dp;
                dpprev = dp;
            }
            if ((q & 3) == 3) SBAR();
        }
        // junction 2x2: x31 = s*(dp31 - cp31*dq32); x32 = dq32 - eq32*x31
        float other = dpp2(dpprev);
        float dtp = half ? other : dpprev;    // dp31
        float dbt = half ? dpprev : other;    // dq32
        float x31 = smid * fmaf(cptop, dbt, dtp);
        float xj  = half ? fmaf(cpn_own, x31, dpprev) : x31;
        tau[31] = xj;
        // substitution outward (both halves away from the junction)
        float xn = xj;
        #pragma unroll
        for (int q = 7; q >= 0; --q) {
            uint2 c4 = CPsh[q * 256 + slot];
            #pragma unroll
            for (int i = 3; i >= 0; --i) {
                const int j = 4*q + i;
                if (j == 31) continue;        // junction already solved
                float cv = (i == 0) ? lo16f(c4.x) : (i == 1) ? hi16f(c4.x)
                         : (i == 2) ? lo16f(c4.y) : hi16f(c4.y);
                float x = fmaf(cv, xn, tau[j]);
                tau[j] = x;
                xn = x;
            }
            if ((q & 3) == 0) SBAR();
        }
    }

    // ---- store f32 output: out[field][col][k] (bottom reversed) ----
    float* op = out + ((size_t)field * NCOLS + col) * NZ;
    if (!half) {
        #pragma unroll
        for (int q = 0; q < 8; ++q) {
            float4 w;
            w.x = tau[4*q+0] + meanadd; w.y = tau[4*q+1] + meanadd;
            w.z = tau[4*q+2] + meanadd; w.w = tau[4*q+3] + meanadd;
            ((float4*)op)[q] = w;
        }
    } else {
        #pragma unroll
        for (int q = 0; q < 8; ++q) {
            float4 w;
            w.x = tau[4*q+3] + meanadd; w.y = tau[4*q+2] + meanadd;
            w.z = tau[4*q+1] + meanadd; w.w = tau[4*q+0] + meanadd;
            ((float4*)op)[15 - q] = w;
        }
    }
}

extern "C" void kernel_launch(void* const* d_in, const int* in_sizes, int n_in,
                              void* d_out, int out_size, void* d_ws, size_t ws_size,
                              hipStream_t stream) {
    const float* u0   = (const float*)d_in[0];
    const float* v0   = (const float*)d_in[1];
    const float* t0   = (const float*)d_in[2];
    const float* s0   = (const float*)d_in[3];
    const float* hz   = (const float*)d_in[4];
    const float* akv  = (const float*)d_in[5];
    const float* akt  = (const float*)d_in[6];
    const float* tfo  = (const float*)d_in[7];
    const float* sfo  = (const float*)d_in[8];
    const float* uss  = (const float*)d_in[9];
    const float* vss  = (const float*)d_in[10];
    const float* usb  = (const float*)d_in[11];
    const float* vsb  = (const float*)d_in[12];
    const float* fcor = (const float*)d_in[13];

    scm_kernel<<<dim3(NCOLS / 64), dim3(512), 0, stream>>>(
        u0, v0, t0, s0, hz, akv, akt, tfo, sfo, uss, vss, usb, vsb, fcor,
        (float*)d_out);
}